// Round 4
// baseline (241.380 us; speedup 1.0000x reference)
//
#include <hip/hip_runtime.h>
#include <math.h>

#define NBINS 182
#define NB 128   // batch

typedef unsigned short u16;
typedef __attribute__((ext_vector_type(8))) short short8;   // 8 bf16 (4 VGPRs)
typedef __attribute__((ext_vector_type(4))) float f32x4;    // MFMA accumulator

__device__ __forceinline__ u16 f2bf(float f) {
    union { float f; unsigned u; } v; v.f = f;
    unsigned r = v.u + 0x7FFF + ((v.u >> 16) & 1);   // RNE
    return (u16)(r >> 16);
}
__device__ __forceinline__ float bf2f(u16 u) {
    union { unsigned u; float f; } v; v.u = ((unsigned)u) << 16;
    return v.f;
}
__device__ __forceinline__ short8 negbf(short8 v) {
    short8 r;
#pragma unroll
    for (int i = 0; i < 8; ++i) r[i] = v[i] ^ (short)0x8000;
    return r;
}

__device__ __forceinline__ int radial_bin(int dx, int dy) {
    int d2 = dx * dx + dy * dy;
    int bin = (int)sqrtf((float)d2);
    while ((bin + 1) * (bin + 1) <= d2) ++bin;
    while (bin * bin > d2) --bin;
    return bin;
}

// ---------------------------------------------------------------------------
// prep: 544 blocks (gray job removed -- s1 now reads x directly).
//   [0,256)      build_M row j (fp64 accum -> M fp32 + A1 bf16)
//   [256,512)    nr partial histogram -> nrpart[row][bin]
//   [512,544)    zero tbin + Tt_im row 128 + done counters
// ---------------------------------------------------------------------------
__global__ __launch_bounds__(256) void prep(float* __restrict__ M_re,
                                            float* __restrict__ M_im,
                                            u16* __restrict__ A1,
                                            float* __restrict__ nrpart,
                                            float* __restrict__ tbin,
                                            u16* __restrict__ Tt_im,
                                            unsigned* __restrict__ done) {
    __shared__ double ctab[1024];
    __shared__ double stab[1024];
    __shared__ float s[NBINS];
    int blk = blockIdx.x;
    int t = threadIdx.x;

    if (blk < 256) {             // ---- build_M ----
        for (int i = t; i < 1024; i += 256) {
            double a = 3.14159265358979323846 * (double)i / 512.0;
            ctab[i] = cos(a);
            stab[i] = sin(a);
        }
        __syncthreads();
        int j = blk;
        int w = t;
        double re = 0.0, im = 0.0;
        int tw = 2 * w + 1;
        for (int k = 0; k < 256; ++k) {
            int e = (4 * j * k) & 1023;
            int m = (tw * k) & 1023;
            double cw = 2.0 * ctab[m];
            re += ctab[e] * cw;
            im -= stab[e] * cw;
        }
        M_re[j * 256 + w] = (float)re;
        M_im[j * 256 + w] = (float)im;
        A1[j * 256 + w] = f2bf((float)re);
        A1[(j + 256) * 256 + w] = f2bf((float)im);
    } else if (blk < 512) {      // ---- nr partial histogram, row i ----
        int i = blk - 256;
        if (t < NBINS) s[t] = 0.0f;
        __syncthreads();
        int bin = radial_bin(t - 128, i - 128);
        atomicAdd(&s[bin], 1.0f);
        __syncthreads();
        if (t < NBINS) nrpart[i * NBINS + t] = s[t];
    } else {                     // ---- zeros ----
        int idx = (blk - 512) * 256 + t;          // 0..8191
        for (int i = idx; i < NB * NBINS; i += 8192) tbin[i] = 0.0f;
        for (int i = idx; i < NB * 128; i += 8192) {
            int bb = i >> 7, off = (i & 127) << 1;
            *(unsigned*)(Tt_im + (size_t)bb * 65536 + 128 * 256 + off) = 0u;
        }
        if (idx < NB) done[idx] = 0u;
    }
}

// ---------------------------------------------------------------------------
// Stage 1 (MFMA), gray fused: Tt[r][h] = sum_w A1[r,w] * gray(x)[b,h,w].
// Grid (2,1,NB), 512 threads (8 waves).  Per block (batch b, h-half h0):
//   - stage A1 slices for re rows 0..127, im rows 256..383, and rows 128..143
//     (row-128 replay) into As[272][40]; compute gray bf16 of x[b,:,h0+row,kk
//     slice] into Bs[128][40] with the VERBATIM luma expression from the old
//     prep (same expression tree -> same FMA contraction -> bit-identical G).
//   - waves 0..3: re 128x128 tile; waves 4..7: im; +1 MFMA/wave/kk for the
//     bit-exact row-128 replay (same A rows 128+fr, same kk order as before).
// Removes the G buffer entirely (33.5 MB write + ~70 MB re-read).
// ---------------------------------------------------------------------------
__global__ __launch_bounds__(512) void s1(const u16* __restrict__ A1,
                                          const float* __restrict__ x,
                                          u16* __restrict__ Tt_re,
                                          u16* __restrict__ Tt_im) {
    __shared__ u16 As[272 * 40];   // rows: 0..127 re, 128..255 im, 256..271 row128
    __shared__ u16 Bs[128 * 40];
    int b = blockIdx.z;
    int h0 = blockIdx.x * 128;
    int t = threadIdx.x;
    int lane = t & 63, wv = t >> 6;
    int w4 = wv & 3;
    int wr = (w4 >> 1) * 64;
    int wc = (w4 & 1) * 64;
    int aOff = (wv >= 4) ? 128 : 0;
    int fr = lane & 15;
    int fk = (lane >> 4) << 3;

    f32x4 acc[4][4];
#pragma unroll
    for (int i = 0; i < 4; ++i)
#pragma unroll
        for (int j = 0; j < 4; ++j) acc[i][j] = (f32x4){0.f, 0.f, 0.f, 0.f};
    f32x4 acc128 = (f32x4){0.f, 0.f, 0.f, 0.f};

    int srow = t >> 2, swq = (t & 3) << 3;     // B-stage: row 0..127, 8 cols
    const float* xp = x + (size_t)b * 196608 + (size_t)(h0 + srow) * 256 + swq;

    for (int kk = 0; kk < 256; kk += 32) {
        // ---- A stage: 272 rows x 32 cols ----
        for (int c = t; c < 1088; c += 512) {
            int row = c >> 2, off = (c & 3) << 3;
            int src = (row < 128) ? row : ((row < 256) ? row + 128 : row - 128);
            *(uint4*)&As[row * 40 + off] =
                *(const uint4*)(A1 + (size_t)src * 256 + kk + off);
        }
        // ---- B stage: gray(x) slice, 128 rows x 32 cols ----
        {
            const float* p = xp + kk;
            float4 ra = *(const float4*)p;
            float4 rb = *(const float4*)(p + 4);
            float4 ga = *(const float4*)(p + 65536);
            float4 gb = *(const float4*)(p + 65540);
            float4 ba = *(const float4*)(p + 131072);
            float4 bb = *(const float4*)(p + 131076);
            float q0 = 0.2989f * ra.x + 0.587f * ga.x + 0.114f * ba.x;
            float q1 = 0.2989f * ra.y + 0.587f * ga.y + 0.114f * ba.y;
            float q2 = 0.2989f * ra.z + 0.587f * ga.z + 0.114f * ba.z;
            float q3 = 0.2989f * ra.w + 0.587f * ga.w + 0.114f * ba.w;
            float q4 = 0.2989f * rb.x + 0.587f * gb.x + 0.114f * bb.x;
            float q5 = 0.2989f * rb.y + 0.587f * gb.y + 0.114f * bb.y;
            float q6 = 0.2989f * rb.z + 0.587f * gb.z + 0.114f * bb.z;
            float q7 = 0.2989f * rb.w + 0.587f * gb.w + 0.114f * bb.w;
            uint4 o;
            o.x = (unsigned)f2bf(q0) | ((unsigned)f2bf(q1) << 16);
            o.y = (unsigned)f2bf(q2) | ((unsigned)f2bf(q3) << 16);
            o.z = (unsigned)f2bf(q4) | ((unsigned)f2bf(q5) << 16);
            o.w = (unsigned)f2bf(q6) | ((unsigned)f2bf(q7) << 16);
            *(uint4*)&Bs[srow * 40 + swq] = o;
        }
        __syncthreads();
        short8 af[4], bfr[4];
#pragma unroll
        for (int i = 0; i < 4; ++i)
            af[i] = *(const short8*)&As[(aOff + wr + i * 16 + fr) * 40 + fk];
#pragma unroll
        for (int j = 0; j < 4; ++j)
            bfr[j] = *(const short8*)&Bs[(wc + j * 16 + fr) * 40 + fk];
#pragma unroll
        for (int i = 0; i < 4; ++i)
#pragma unroll
            for (int j = 0; j < 4; ++j)
                acc[i][j] = __builtin_amdgcn_mfma_f32_16x16x32_bf16(
                    af[i], bfr[j], acc[i][j], 0, 0, 0);
        // row-128 replay: 1 MFMA per wave per kk (16-col tile at wv*16)
        {
            short8 a128 = *(const short8*)&As[(256 + fr) * 40 + fk];
            short8 b128 = *(const short8*)&Bs[(wv * 16 + fr) * 40 + fk];
            acc128 = __builtin_amdgcn_mfma_f32_16x16x32_bf16(
                a128, b128, acc128, 0, 0, 0);
        }
        __syncthreads();
    }

    u16* dst = ((wv < 4) ? Tt_re : Tt_im) + (size_t)b * 65536;
    int rq = (lane >> 4) << 2;
#pragma unroll
    for (int i = 0; i < 4; ++i)
#pragma unroll
        for (int j = 0; j < 4; ++j) {
            int col = h0 + wc + j * 16 + fr;
#pragma unroll
            for (int reg = 0; reg < 4; ++reg) {
                int row = wr + i * 16 + rq + reg;      // 0..127
                dst[(size_t)row * 256 + col] = f2bf(acc[i][j][reg]);
            }
        }
    if ((lane >> 4) == 0)        // fragment row 0 == Tt row 128 (reg 0)
        Tt_re[(size_t)b * 65536 + 128 * 256 + h0 + wv * 16 + fr] = f2bf(acc128[0]);
}

// ---------------------------------------------------------------------------
// s2f: fused stage-2 GEMM (blocks [0,1024)) + row128 (blocks [1024,1152))
// + in-kernel finalize: the 9th (last-arriving) block per batch computes
// prof/min-max/dot and writes out[b].  tbin is read back via device-scope
// atomic reads (cross-XCD coherent); arrival counter ordered by the barrier
// (drains outstanding atomics) + __threadfence().
// ---------------------------------------------------------------------------
__global__ __launch_bounds__(256) void s2f(const u16* __restrict__ A1,
                                           const float* __restrict__ M_re,
                                           const u16* __restrict__ Tt_re,
                                           const u16* __restrict__ Tt_im,
                                           float* __restrict__ tbin,
                                           const float* __restrict__ nrpart,
                                           const float* __restrict__ wgt,
                                           const float* __restrict__ bias,
                                           float* __restrict__ out,
                                           unsigned* __restrict__ done) {
    __shared__ u16 Ar[64 * 40], Ai[64 * 40], Br[64 * 40], Bi[64 * 40];
    __shared__ float sbins[NBINS];
    __shared__ float sM[256];
    __shared__ float prof[NBINS];
    __shared__ float smn, smx, ssum;
    __shared__ int sOld;
    int blk = blockIdx.x;
    int t = threadIdx.x;
    int b;

    if (blk >= 1024) {           // ---- row128 ----
        b = blk - 1024;
        sM[t] = M_re[128 * 256 + t];
        __syncthreads();
        if (t <= 128) {
            const u16* pr = Tt_re + (size_t)b * 65536 + (size_t)t * 256;
            const u16* pi = Tt_im + (size_t)b * 65536 + (size_t)t * 256;
            float re = 0.0f, im = 0.0f;
            for (int h = 0; h < 256; h += 8) {
                uint4 vr = *(const uint4*)(pr + h);
                uint4 vi = *(const uint4*)(pi + h);
                unsigned wr[4] = {vr.x, vr.y, vr.z, vr.w};
                unsigned wi[4] = {vi.x, vi.y, vi.z, vi.w};
#pragma unroll
                for (int q = 0; q < 4; ++q) {
                    re = fmaf(sM[h + 2 * q], bf2f((u16)(wr[q] & 0xffff)), re);
                    re = fmaf(sM[h + 2 * q + 1], bf2f((u16)(wr[q] >> 16)), re);
                    im = fmaf(sM[h + 2 * q], bf2f((u16)(wi[q] & 0xffff)), im);
                    im = fmaf(sM[h + 2 * q + 1], bf2f((u16)(wi[q] >> 16)), im);
                }
            }
            re += 1e-8f; im += 1e-8f;
            float mag = logf(sqrtf(re * re + im * im + 1e-10f) + 1e-10f);
            float wj = (t == 0 || t == 128) ? 1.0f : 2.0f;
            int dx = (t < 128) ? t : t - 256;
            int bin = radial_bin(dx, -128);
            atomicAdd(&tbin[b * NBINS + bin], wj * mag);
        }
    } else {
        // ---- s2 GEMM ----
        b = blk >> 3;
        int u0 = ((blk >> 2) & 1) * 64;
        int j0 = (blk & 3) * 64;
        int lane = t & 63, wv = t >> 6;
        int wu = (wv >> 1) * 32;
        int wj = (wv & 1) * 32;
        int fr = lane & 15;
        int fk = (lane >> 4) << 3;

        for (int i = t; i < NBINS; i += 256) sbins[i] = 0.0f;

        f32x4 accr[2][2], acci[2][2];
#pragma unroll
        for (int i = 0; i < 2; ++i)
#pragma unroll
            for (int j = 0; j < 2; ++j) {
                accr[i][j] = (f32x4){0.f, 0.f, 0.f, 0.f};
                acci[i][j] = (f32x4){0.f, 0.f, 0.f, 0.f};
            }

        const u16* Apr = A1 + (size_t)u0 * 256;
        const u16* Api = A1 + (size_t)(256 + u0) * 256;

        int lrow = t >> 2, loff = (t & 3) << 3;
        int jp = j0 + lrow;                        // 0..255
        int src = (jp <= 128) ? jp : 256 - jp;     // mirror source row
        unsigned imask = (jp > 128) ? 0x80008000u : 0u;  // bf16-pair sign flip
        const u16* Trs = Tt_re + (size_t)b * 65536 + (size_t)src * 256;
        const u16* Tis = Tt_im + (size_t)b * 65536 + (size_t)src * 256;

        for (int kk = 0; kk < 256; kk += 32) {
            *(uint4*)&Ar[lrow * 40 + loff] =
                *(const uint4*)(Apr + (size_t)lrow * 256 + kk + loff);
            *(uint4*)&Ai[lrow * 40 + loff] =
                *(const uint4*)(Api + (size_t)lrow * 256 + kk + loff);
            *(uint4*)&Br[lrow * 40 + loff] = *(const uint4*)(Trs + kk + loff);
            uint4 vi = *(const uint4*)(Tis + kk + loff);
            vi.x ^= imask; vi.y ^= imask; vi.z ^= imask; vi.w ^= imask;
            *(uint4*)&Bi[lrow * 40 + loff] = vi;
            __syncthreads();
            short8 arf[2], aif[2], naif[2], brf[2], bif[2];
#pragma unroll
            for (int i = 0; i < 2; ++i) {
                arf[i] = *(const short8*)&Ar[(wu + i * 16 + fr) * 40 + fk];
                aif[i] = *(const short8*)&Ai[(wu + i * 16 + fr) * 40 + fk];
                naif[i] = negbf(aif[i]);
            }
#pragma unroll
            for (int j = 0; j < 2; ++j) {
                brf[j] = *(const short8*)&Br[(wj + j * 16 + fr) * 40 + fk];
                bif[j] = *(const short8*)&Bi[(wj + j * 16 + fr) * 40 + fk];
            }
#pragma unroll
            for (int i = 0; i < 2; ++i)
#pragma unroll
                for (int j = 0; j < 2; ++j) {
                    accr[i][j] = __builtin_amdgcn_mfma_f32_16x16x32_bf16(
                        arf[i], brf[j], accr[i][j], 0, 0, 0);
                    accr[i][j] = __builtin_amdgcn_mfma_f32_16x16x32_bf16(
                        naif[i], bif[j], accr[i][j], 0, 0, 0);
                    acci[i][j] = __builtin_amdgcn_mfma_f32_16x16x32_bf16(
                        arf[i], bif[j], acci[i][j], 0, 0, 0);
                    acci[i][j] = __builtin_amdgcn_mfma_f32_16x16x32_bf16(
                        aif[i], brf[j], acci[i][j], 0, 0, 0);
                }
            __syncthreads();
        }

        int rq = (lane >> 4) << 2;
#pragma unroll
        for (int i = 0; i < 2; ++i)
#pragma unroll
            for (int j = 0; j < 2; ++j) {
                int v = j0 + wj + j * 16 + fr;
                int dx = (v < 128) ? v : v - 256;
#pragma unroll
                for (int reg = 0; reg < 4; ++reg) {
                    int u = u0 + wu + i * 16 + rq + reg;   // 0..127
                    float wrow = (u == 0) ? 1.0f : 2.0f;
                    int bin = radial_bin(dx, u);
                    float re = accr[i][j][reg] + 1e-8f;
                    float im = acci[i][j][reg] + 1e-8f;
                    float mag = logf(sqrtf(re * re + im * im + 1e-10f) + 1e-10f);
                    atomicAdd(&sbins[bin], wrow * mag);
                }
            }
        __syncthreads();
        for (int i = t; i < NBINS; i += 256)
            atomicAdd(&tbin[b * NBINS + i], sbins[i]);
    }

    // ---- arrival counter; 9th block per batch finalizes ----
    __syncthreads();                     // drains this block's tbin atomics
    if (t == 0) {
        __threadfence();
        sOld = (int)atomicAdd(&done[b], 1u);
    }
    __syncthreads();
    if (sOld == 8) {
        if (t < NBINS) {
            float nr = 0.0f;
            for (int i = 0; i < 256; ++i) nr += nrpart[i * NBINS + t];
            float tb = atomicAdd(&tbin[b * NBINS + t], 0.0f);   // coherent read
            prof[t] = tb / (nr + 1e-10f);
        }
        __syncthreads();
        if (t == 0) {
            float mn = prof[1], mx = prof[1];
            for (int i = 2; i <= 179; ++i) {
                float p = prof[i];
                mn = fminf(mn, p);
                mx = fmaxf(mx, p);
            }
            smn = mn; smx = mx; ssum = 0.0f;
        }
        __syncthreads();
        if (t < 90) {
            float denom = smx - smn;
            float v = (prof[90 + t] - smn) / denom;
            if (v != v) v = 0.0f;
            atomicAdd(&ssum, v * wgt[t]);
        }
        __syncthreads();
        if (t == 0) out[b] = ssum + bias[0];
    }
}

// ---------------------------------------------------------------------------
extern "C" void kernel_launch(void* const* d_in, const int* in_sizes, int n_in,
                              void* d_out, int out_size, void* d_ws, size_t ws_size,
                              hipStream_t stream) {
    const float* x = (const float*)d_in[0];     // (128,3,256,256)
    const float* w = (const float*)d_in[1];     // (1,90)
    const float* bias = (const float*)d_in[2];  // (1,)
    float* out = (float*)d_out;                 // (128,1)

    float* M_re = (float*)d_ws;                    // 65536 f
    float* M_im = M_re + 65536;                    // 65536 f
    u16* A1 = (u16*)(M_im + 65536);                // 512*256 u16
    u16* Tt_re = A1 + 131072;                      // 128*65536 u16 (rows 0..128 used)
    u16* Tt_im = Tt_re + (size_t)NB * 65536;       // 128*65536 u16 (rows 0..128 used)
    float* tbin = (float*)(Tt_im + (size_t)NB * 65536);   // NB*NBINS f
    float* nrpart = tbin + NB * NBINS;             // 256*NBINS f
    unsigned* done = (unsigned*)(nrpart + 256 * NBINS);   // NB u32

    prep<<<544, 256, 0, stream>>>(M_re, M_im, A1, nrpart, tbin, Tt_im, done);
    s1<<<dim3(2, 1, NB), 512, 0, stream>>>(A1, x, Tt_re, Tt_im);
    s2f<<<1152, 256, 0, stream>>>(A1, M_re, Tt_re, Tt_im, tbin,
                                  nrpart, w, bias, out, done);
}

// Round 5
// 232.270 us; speedup vs baseline: 1.0392x; 1.0392x over previous
//
#include <hip/hip_runtime.h>
#include <math.h>

#define NBINS 182
#define NB 128   // batch

typedef unsigned short u16;
typedef __attribute__((ext_vector_type(8))) short short8;   // 8 bf16 (4 VGPRs)
typedef __attribute__((ext_vector_type(4))) float f32x4;    // MFMA accumulator

__device__ __forceinline__ u16 f2bf(float f) {
    union { float f; unsigned u; } v; v.f = f;
    unsigned r = v.u + 0x7FFF + ((v.u >> 16) & 1);   // RNE
    return (u16)(r >> 16);
}
__device__ __forceinline__ float bf2f(u16 u) {
    union { unsigned u; float f; } v; v.u = ((unsigned)u) << 16;
    return v.f;
}
__device__ __forceinline__ short8 negbf(short8 v) {
    short8 r;
#pragma unroll
    for (int i = 0; i < 8; ++i) r[i] = v[i] ^ (short)0x8000;
    return r;
}

__device__ __forceinline__ int radial_bin(int dx, int dy) {
    int d2 = dx * dx + dy * dy;
    int bin = (int)sqrtf((float)d2);
    while ((bin + 1) * (bin + 1) <= d2) ++bin;
    while (bin * bin > d2) --bin;
    return bin;
}

// ---------------------------------------------------------------------------
// prep: 544 blocks.
//   [0,256)      build_M row j (fp64 accum -> M fp32 + A1 bf16)
//   [256,512)    nr partial histogram -> nrpart[row][bin]
//   [512,544)    zero tbin + Tt_im row 128 (bitwise +0, matches old MFMA)
// ---------------------------------------------------------------------------
__global__ __launch_bounds__(256) void prep(float* __restrict__ M_re,
                                            float* __restrict__ M_im,
                                            u16* __restrict__ A1,
                                            float* __restrict__ nrpart,
                                            float* __restrict__ tbin,
                                            u16* __restrict__ Tt_im) {
    __shared__ double ctab[1024];
    __shared__ double stab[1024];
    __shared__ float s[NBINS];
    int blk = blockIdx.x;
    int t = threadIdx.x;

    if (blk < 256) {             // ---- build_M ----
        for (int i = t; i < 1024; i += 256) {
            double a = 3.14159265358979323846 * (double)i / 512.0;
            ctab[i] = cos(a);
            stab[i] = sin(a);
        }
        __syncthreads();
        int j = blk;
        int w = t;
        double re = 0.0, im = 0.0;
        int tw = 2 * w + 1;
        for (int k = 0; k < 256; ++k) {
            int e = (4 * j * k) & 1023;
            int m = (tw * k) & 1023;
            double cw = 2.0 * ctab[m];
            re += ctab[e] * cw;
            im -= stab[e] * cw;
        }
        M_re[j * 256 + w] = (float)re;
        M_im[j * 256 + w] = (float)im;
        A1[j * 256 + w] = f2bf((float)re);
        A1[(j + 256) * 256 + w] = f2bf((float)im);
    } else if (blk < 512) {      // ---- nr partial histogram, row i ----
        int i = blk - 256;
        if (t < NBINS) s[t] = 0.0f;
        __syncthreads();
        int bin = radial_bin(t - 128, i - 128);
        atomicAdd(&s[bin], 1.0f);
        __syncthreads();
        if (t < NBINS) nrpart[i * NBINS + t] = s[t];
    } else {                     // ---- zeros ----
        int idx = (blk - 512) * 256 + t;          // 0..8191
        for (int i = idx; i < NB * NBINS; i += 8192) tbin[i] = 0.0f;
        for (int i = idx; i < NB * 128; i += 8192) {
            int bb = i >> 7, off = (i & 127) << 1;
            *(unsigned*)(Tt_im + (size_t)bb * 65536 + 128 * 256 + off) = 0u;
        }
    }
}

// ---------------------------------------------------------------------------
// Stage 1 (MFMA), gray fused, 2-blocks/CU version:
//   Tt[r][h] = sum_w A1[r,w] * gray(x)[b,h,w]
// Grid (4,1,NB) x 256 thr (4 waves).  Block = batch b, h-quarter h0=64*q.
//   As[272][40]: rows 0..127 re (A1 0..127), 128..255 im (A1 256..383),
//                256..271 row-128 replay (A1 128..143).
//   Bs[64][40]:  gray bf16 of x[b, :, h0+row, kk-slice] -- VERBATIM luma
//                expression (same tree -> same FMA contraction -> bit-
//                identical to the verified G values).
// Wave wv: isIm=wv>>1 selects re/im, rhalf=(wv&1)*64 the row half; 4x4 frags
// of 16x16x32 over 64 rows x 64 cols.  +1 MFMA/wave/kk for the bit-exact
// row-128 replay (A rows 128+fr, same kk order as the verified kernel).
// Same fragment chains as the round-2 kernel -> bit-identical Tt.
// ---------------------------------------------------------------------------
__global__ __launch_bounds__(256) void s1(const u16* __restrict__ A1,
                                          const float* __restrict__ x,
                                          u16* __restrict__ Tt_re,
                                          u16* __restrict__ Tt_im) {
    __shared__ u16 As[272 * 40];
    __shared__ u16 Bs[64 * 40];
    int b = blockIdx.z;
    int h0 = blockIdx.x * 64;
    int t = threadIdx.x;
    int lane = t & 63, wv = t >> 6;        // 4 waves
    int isIm = wv >> 1;
    int rhalf = (wv & 1) * 64;
    int aOff = isIm ? 128 : 0;
    int fr = lane & 15;
    int fk = (lane >> 4) << 3;

    f32x4 acc[4][4];
#pragma unroll
    for (int i = 0; i < 4; ++i)
#pragma unroll
        for (int j = 0; j < 4; ++j) acc[i][j] = (f32x4){0.f, 0.f, 0.f, 0.f};
    f32x4 acc128 = (f32x4){0.f, 0.f, 0.f, 0.f};

    int srow = t >> 2, swq = (t & 3) << 3;     // B-stage: row 0..63, 8 cols
    const float* xp = x + (size_t)b * 196608 + (size_t)(h0 + srow) * 256 + swq;

    for (int kk = 0; kk < 256; kk += 32) {
        // ---- A stage: 272 rows x 32 cols ----
        for (int c = t; c < 1088; c += 256) {
            int row = c >> 2, off = (c & 3) << 3;
            int src = (row < 128) ? row : ((row < 256) ? row + 128 : row - 128);
            *(uint4*)&As[row * 40 + off] =
                *(const uint4*)(A1 + (size_t)src * 256 + kk + off);
        }
        // ---- B stage: gray(x) slice, 64 rows x 32 cols ----
        {
            const float* p = xp + kk;
            float4 ra = *(const float4*)p;
            float4 rb = *(const float4*)(p + 4);
            float4 ga = *(const float4*)(p + 65536);
            float4 gb = *(const float4*)(p + 65540);
            float4 ba = *(const float4*)(p + 131072);
            float4 bb = *(const float4*)(p + 131076);
            float q0 = 0.2989f * ra.x + 0.587f * ga.x + 0.114f * ba.x;
            float q1 = 0.2989f * ra.y + 0.587f * ga.y + 0.114f * ba.y;
            float q2 = 0.2989f * ra.z + 0.587f * ga.z + 0.114f * ba.z;
            float q3 = 0.2989f * ra.w + 0.587f * ga.w + 0.114f * ba.w;
            float q4 = 0.2989f * rb.x + 0.587f * gb.x + 0.114f * bb.x;
            float q5 = 0.2989f * rb.y + 0.587f * gb.y + 0.114f * bb.y;
            float q6 = 0.2989f * rb.z + 0.587f * gb.z + 0.114f * bb.z;
            float q7 = 0.2989f * rb.w + 0.587f * gb.w + 0.114f * bb.w;
            uint4 o;
            o.x = (unsigned)f2bf(q0) | ((unsigned)f2bf(q1) << 16);
            o.y = (unsigned)f2bf(q2) | ((unsigned)f2bf(q3) << 16);
            o.z = (unsigned)f2bf(q4) | ((unsigned)f2bf(q5) << 16);
            o.w = (unsigned)f2bf(q6) | ((unsigned)f2bf(q7) << 16);
            *(uint4*)&Bs[srow * 40 + swq] = o;
        }
        __syncthreads();
        short8 af[4], bfr[4];
#pragma unroll
        for (int i = 0; i < 4; ++i)
            af[i] = *(const short8*)&As[(aOff + rhalf + i * 16 + fr) * 40 + fk];
#pragma unroll
        for (int j = 0; j < 4; ++j)
            bfr[j] = *(const short8*)&Bs[(j * 16 + fr) * 40 + fk];
#pragma unroll
        for (int i = 0; i < 4; ++i)
#pragma unroll
            for (int j = 0; j < 4; ++j)
                acc[i][j] = __builtin_amdgcn_mfma_f32_16x16x32_bf16(
                    af[i], bfr[j], acc[i][j], 0, 0, 0);
        // row-128 replay: 1 MFMA per wave per kk (16-col subtile at wv*16)
        {
            short8 a128 = *(const short8*)&As[(256 + fr) * 40 + fk];
            short8 b128 = *(const short8*)&Bs[(wv * 16 + fr) * 40 + fk];
            acc128 = __builtin_amdgcn_mfma_f32_16x16x32_bf16(
                a128, b128, acc128, 0, 0, 0);
        }
        __syncthreads();
    }

    u16* dst = (isIm ? Tt_im : Tt_re) + (size_t)b * 65536;
    int rq = (lane >> 4) << 2;
#pragma unroll
    for (int i = 0; i < 4; ++i)
#pragma unroll
        for (int j = 0; j < 4; ++j) {
            int col = h0 + j * 16 + fr;
#pragma unroll
            for (int reg = 0; reg < 4; ++reg) {
                int row = rhalf + i * 16 + rq + reg;   // 0..127
                dst[(size_t)row * 256 + col] = f2bf(acc[i][j][reg]);
            }
        }
    if ((lane >> 4) == 0)        // fragment row 0 == Tt row 128 (reg 0)
        Tt_re[(size_t)b * 65536 + 128 * 256 + h0 + wv * 16 + fr] = f2bf(acc128[0]);
}

// ---------------------------------------------------------------------------
// s2f: fused stage-2 GEMM (blocks [0,1024)) + row128 (blocks [1024,1152)).
// Round-2 verified form (no fence / no in-kernel finalize).  B-tile staging
// for j0 in {128,192} mirrors source row 256-j with im sign-flip (bitwise
// identical to what a full stage 1 would have written).
// ---------------------------------------------------------------------------
__global__ __launch_bounds__(256) void s2f(const u16* __restrict__ A1,
                                           const float* __restrict__ M_re,
                                           const u16* __restrict__ Tt_re,
                                           const u16* __restrict__ Tt_im,
                                           float* __restrict__ tbin) {
    __shared__ u16 Ar[64 * 40], Ai[64 * 40], Br[64 * 40], Bi[64 * 40];
    __shared__ float sbins[NBINS];
    __shared__ float sM[256];
    int blk = blockIdx.x;
    int t = threadIdx.x;

    if (blk >= 1024) {           // ---- row128 ----
        int b = blk - 1024;
        sM[t] = M_re[128 * 256 + t];
        __syncthreads();
        if (t > 128) return;
        const u16* pr = Tt_re + (size_t)b * 65536 + (size_t)t * 256;
        const u16* pi = Tt_im + (size_t)b * 65536 + (size_t)t * 256;
        float re = 0.0f, im = 0.0f;
        for (int h = 0; h < 256; h += 8) {
            uint4 vr = *(const uint4*)(pr + h);
            uint4 vi = *(const uint4*)(pi + h);
            unsigned wr[4] = {vr.x, vr.y, vr.z, vr.w};
            unsigned wi[4] = {vi.x, vi.y, vi.z, vi.w};
#pragma unroll
            for (int q = 0; q < 4; ++q) {
                re = fmaf(sM[h + 2 * q], bf2f((u16)(wr[q] & 0xffff)), re);
                re = fmaf(sM[h + 2 * q + 1], bf2f((u16)(wr[q] >> 16)), re);
                im = fmaf(sM[h + 2 * q], bf2f((u16)(wi[q] & 0xffff)), im);
                im = fmaf(sM[h + 2 * q + 1], bf2f((u16)(wi[q] >> 16)), im);
            }
        }
        re += 1e-8f; im += 1e-8f;
        float mag = logf(sqrtf(re * re + im * im + 1e-10f) + 1e-10f);
        float wj = (t == 0 || t == 128) ? 1.0f : 2.0f;
        int dx = (t < 128) ? t : t - 256;
        int bin = radial_bin(dx, -128);
        atomicAdd(&tbin[b * NBINS + bin], wj * mag);
        return;
    }

    // ---- s2 GEMM ----
    int b = blk >> 3;
    int u0 = ((blk >> 2) & 1) * 64;
    int j0 = (blk & 3) * 64;
    int lane = t & 63, wv = t >> 6;
    int wu = (wv >> 1) * 32;
    int wj = (wv & 1) * 32;
    int fr = lane & 15;
    int fk = (lane >> 4) << 3;

    for (int i = t; i < NBINS; i += 256) sbins[i] = 0.0f;

    f32x4 accr[2][2], acci[2][2];
#pragma unroll
    for (int i = 0; i < 2; ++i)
#pragma unroll
        for (int j = 0; j < 2; ++j) {
            accr[i][j] = (f32x4){0.f, 0.f, 0.f, 0.f};
            acci[i][j] = (f32x4){0.f, 0.f, 0.f, 0.f};
        }

    const u16* Apr = A1 + (size_t)u0 * 256;
    const u16* Api = A1 + (size_t)(256 + u0) * 256;

    int lrow = t >> 2, loff = (t & 3) << 3;
    int jp = j0 + lrow;                        // 0..255
    int src = (jp <= 128) ? jp : 256 - jp;     // mirror source row
    unsigned imask = (jp > 128) ? 0x80008000u : 0u;  // bf16-pair sign flip
    const u16* Trs = Tt_re + (size_t)b * 65536 + (size_t)src * 256;
    const u16* Tis = Tt_im + (size_t)b * 65536 + (size_t)src * 256;

    for (int kk = 0; kk < 256; kk += 32) {
        *(uint4*)&Ar[lrow * 40 + loff] =
            *(const uint4*)(Apr + (size_t)lrow * 256 + kk + loff);
        *(uint4*)&Ai[lrow * 40 + loff] =
            *(const uint4*)(Api + (size_t)lrow * 256 + kk + loff);
        *(uint4*)&Br[lrow * 40 + loff] = *(const uint4*)(Trs + kk + loff);
        uint4 vi = *(const uint4*)(Tis + kk + loff);
        vi.x ^= imask; vi.y ^= imask; vi.z ^= imask; vi.w ^= imask;
        *(uint4*)&Bi[lrow * 40 + loff] = vi;
        __syncthreads();
        short8 arf[2], aif[2], naif[2], brf[2], bif[2];
#pragma unroll
        for (int i = 0; i < 2; ++i) {
            arf[i] = *(const short8*)&Ar[(wu + i * 16 + fr) * 40 + fk];
            aif[i] = *(const short8*)&Ai[(wu + i * 16 + fr) * 40 + fk];
            naif[i] = negbf(aif[i]);
        }
#pragma unroll
        for (int j = 0; j < 2; ++j) {
            brf[j] = *(const short8*)&Br[(wj + j * 16 + fr) * 40 + fk];
            bif[j] = *(const short8*)&Bi[(wj + j * 16 + fr) * 40 + fk];
        }
#pragma unroll
        for (int i = 0; i < 2; ++i)
#pragma unroll
            for (int j = 0; j < 2; ++j) {
                accr[i][j] = __builtin_amdgcn_mfma_f32_16x16x32_bf16(
                    arf[i], brf[j], accr[i][j], 0, 0, 0);
                accr[i][j] = __builtin_amdgcn_mfma_f32_16x16x32_bf16(
                    naif[i], bif[j], accr[i][j], 0, 0, 0);
                acci[i][j] = __builtin_amdgcn_mfma_f32_16x16x32_bf16(
                    arf[i], bif[j], acci[i][j], 0, 0, 0);
                acci[i][j] = __builtin_amdgcn_mfma_f32_16x16x32_bf16(
                    aif[i], brf[j], acci[i][j], 0, 0, 0);
            }
        __syncthreads();
    }

    int rq = (lane >> 4) << 2;
#pragma unroll
    for (int i = 0; i < 2; ++i)
#pragma unroll
        for (int j = 0; j < 2; ++j) {
            int v = j0 + wj + j * 16 + fr;
            int dx = (v < 128) ? v : v - 256;
#pragma unroll
            for (int reg = 0; reg < 4; ++reg) {
                int u = u0 + wu + i * 16 + rq + reg;   // 0..127
                float wrow = (u == 0) ? 1.0f : 2.0f;
                int bin = radial_bin(dx, u);
                float re = accr[i][j][reg] + 1e-8f;
                float im = acci[i][j][reg] + 1e-8f;
                float mag = logf(sqrtf(re * re + im * im + 1e-10f) + 1e-10f);
                atomicAdd(&sbins[bin], wrow * mag);
            }
        }
    __syncthreads();
    for (int i = t; i < NBINS; i += 256)
        atomicAdd(&tbin[b * NBINS + i], sbins[i]);
}

// ---------------------------------------------------------------------------
// Finalize: nr = column-sum of nrpart; prof = tbin/nr; min-max over 1..179;
// dot bins 90..179 with w.
// ---------------------------------------------------------------------------
__global__ __launch_bounds__(192) void finalize(const float* __restrict__ tbin,
                                                const float* __restrict__ nrpart,
                                                const float* __restrict__ w,
                                                const float* __restrict__ bias,
                                                float* __restrict__ out) {
    __shared__ float prof[NBINS];
    __shared__ float smn, smx, ssum;
    int b = blockIdx.x;
    int t = threadIdx.x;
    if (t < NBINS) {
        float nr = 0.0f;
        for (int i = 0; i < 256; ++i) nr += nrpart[i * NBINS + t];
        prof[t] = tbin[b * NBINS + t] / (nr + 1e-10f);
    }
    __syncthreads();
    if (t == 0) {
        float mn = prof[1], mx = prof[1];
        for (int i = 2; i <= 179; ++i) {
            float p = prof[i];
            mn = fminf(mn, p);
            mx = fmaxf(mx, p);
        }
        smn = mn; smx = mx; ssum = 0.0f;
    }
    __syncthreads();
    if (t < 90) {
        float denom = smx - smn;
        float v = (prof[90 + t] - smn) / denom;
        if (v != v) v = 0.0f;
        atomicAdd(&ssum, v * w[t]);
    }
    __syncthreads();
    if (t == 0) out[b] = ssum + bias[0];
}

// ---------------------------------------------------------------------------
extern "C" void kernel_launch(void* const* d_in, const int* in_sizes, int n_in,
                              void* d_out, int out_size, void* d_ws, size_t ws_size,
                              hipStream_t stream) {
    const float* x = (const float*)d_in[0];     // (128,3,256,256)
    const float* w = (const float*)d_in[1];     // (1,90)
    const float* bias = (const float*)d_in[2];  // (1,)
    float* out = (float*)d_out;                 // (128,1)

    float* M_re = (float*)d_ws;                    // 65536 f
    float* M_im = M_re + 65536;                    // 65536 f
    u16* A1 = (u16*)(M_im + 65536);                // 512*256 u16
    u16* Tt_re = A1 + 131072;                      // 128*65536 u16 (rows 0..128 used)
    u16* Tt_im = Tt_re + (size_t)NB * 65536;       // 128*65536 u16 (rows 0..128 used)
    float* tbin = (float*)(Tt_im + (size_t)NB * 65536);   // NB*NBINS f
    float* nrpart = tbin + NB * NBINS;             // 256*NBINS f

    prep<<<544, 256, 0, stream>>>(M_re, M_im, A1, nrpart, tbin, Tt_im);
    s1<<<dim3(4, 1, NB), 256, 0, stream>>>(A1, x, Tt_re, Tt_im);
    s2f<<<1152, 256, 0, stream>>>(A1, M_re, Tt_re, Tt_im, tbin);
    finalize<<<NB, 192, 0, stream>>>(tbin, nrpart, w, bias, out);
}

// Round 6
// 208.519 us; speedup vs baseline: 1.1576x; 1.1139x over previous
//
#include <hip/hip_runtime.h>
#include <math.h>

#define NBINS 182
#define NB 128   // batch

typedef unsigned short u16;
typedef __attribute__((ext_vector_type(8))) short short8;   // 8 bf16 (4 VGPRs)
typedef __attribute__((ext_vector_type(4))) float f32x4;    // MFMA accumulator

__device__ __forceinline__ u16 f2bf(float f) {
    union { float f; unsigned u; } v; v.f = f;
    unsigned r = v.u + 0x7FFF + ((v.u >> 16) & 1);   // RNE
    return (u16)(r >> 16);
}
__device__ __forceinline__ float bf2f(u16 u) {
    union { unsigned u; float f; } v; v.u = ((unsigned)u) << 16;
    return v.f;
}
__device__ __forceinline__ short8 negbf(short8 v) {
    short8 r;
#pragma unroll
    for (int i = 0; i < 8; ++i) r[i] = v[i] ^ (short)0x8000;
    return r;
}

__device__ __forceinline__ int radial_bin(int dx, int dy) {
    int d2 = dx * dx + dy * dy;
    int bin = (int)sqrtf((float)d2);
    while ((bin + 1) * (bin + 1) <= d2) ++bin;
    while (bin * bin > d2) --bin;
    return bin;
}

// ---------------------------------------------------------------------------
// prep (round-2 verified form): one launch, 4 jobs by block range.
//   [0,256)      build_M row j (fp64 accum -> M fp32 + A1 bf16)
//   [256,512)    nr partial histogram -> nrpart[row][bin]
//   [512,544)    zero tbin + Tt_im row 128 (bitwise +0, matches old MFMA)
//   [544,1568)   gray grid-stride: G = luma(x) bf16
// ---------------------------------------------------------------------------
__global__ __launch_bounds__(256) void prep(const float* __restrict__ x,
                                            u16* __restrict__ G,
                                            float* __restrict__ M_re,
                                            float* __restrict__ M_im,
                                            u16* __restrict__ A1,
                                            float* __restrict__ nrpart,
                                            float* __restrict__ tbin,
                                            u16* __restrict__ Tt_im) {
    __shared__ double ctab[1024];
    __shared__ double stab[1024];
    __shared__ float s[NBINS];
    int blk = blockIdx.x;
    int t = threadIdx.x;

    if (blk < 256) {             // ---- build_M ----
        for (int i = t; i < 1024; i += 256) {
            double a = 3.14159265358979323846 * (double)i / 512.0;
            ctab[i] = cos(a);
            stab[i] = sin(a);
        }
        __syncthreads();
        int j = blk;
        int w = t;
        double re = 0.0, im = 0.0;
        int tw = 2 * w + 1;
        for (int k = 0; k < 256; ++k) {
            int e = (4 * j * k) & 1023;
            int m = (tw * k) & 1023;
            double cw = 2.0 * ctab[m];
            re += ctab[e] * cw;
            im -= stab[e] * cw;
        }
        M_re[j * 256 + w] = (float)re;
        M_im[j * 256 + w] = (float)im;
        A1[j * 256 + w] = f2bf((float)re);
        A1[(j + 256) * 256 + w] = f2bf((float)im);
    } else if (blk < 512) {      // ---- nr partial histogram, row i ----
        int i = blk - 256;
        if (t < NBINS) s[t] = 0.0f;
        __syncthreads();
        int bin = radial_bin(t - 128, i - 128);
        atomicAdd(&s[bin], 1.0f);
        __syncthreads();
        if (t < NBINS) nrpart[i * NBINS + t] = s[t];
    } else if (blk < 544) {      // ---- zero tbin + Tt_im row 128 ----
        int idx = (blk - 512) * 256 + t;
        for (int i = idx; i < NB * NBINS; i += 32 * 256) tbin[i] = 0.0f;
        for (int i = idx; i < NB * 128; i += 32 * 256) {
            int bb = i >> 7, off = (i & 127) << 1;
            *(unsigned*)(Tt_im + (size_t)bb * 65536 + 128 * 256 + off) = 0u;
        }
    } else {                     // ---- gray, grid-stride ----
        int tid = (blk - 544) * 256 + t;          // 0..262143
        for (int i = tid; i < 2097152; i += 262144) {   // 8 iters
            int idx = i * 4;
            int b = idx >> 16;
            int rem = idx & 65535;
            const float* p = x + (size_t)b * 196608 + rem;
            float4 r = *(const float4*)p;
            float4 g = *(const float4*)(p + 65536);
            float4 bl = *(const float4*)(p + 131072);
            float g0 = 0.2989f * r.x + 0.587f * g.x + 0.114f * bl.x;
            float g1 = 0.2989f * r.y + 0.587f * g.y + 0.114f * bl.y;
            float g2 = 0.2989f * r.z + 0.587f * g.z + 0.114f * bl.z;
            float g3 = 0.2989f * r.w + 0.587f * g.w + 0.114f * bl.w;
            uint2 o;
            o.x = (unsigned)f2bf(g0) | ((unsigned)f2bf(g1) << 16);
            o.y = (unsigned)f2bf(g2) | ((unsigned)f2bf(g3) << 16);
            *(uint2*)(G + idx) = o;
        }
    }
}

// ---------------------------------------------------------------------------
// Stage 1 (round-2 verified form): Tt[r][h] = sum_w A1[r,w] * G[b,h,w].
// y=0: re rows 0..127; y=1: im rows 0..127; y=2: bit-exact row-128 replay.
// ---------------------------------------------------------------------------
__global__ __launch_bounds__(256) void s1(const u16* __restrict__ A1,
                                          const u16* __restrict__ G,
                                          u16* __restrict__ Tt_re,
                                          u16* __restrict__ Tt_im) {
    int b = blockIdx.z;
    int t = threadIdx.x;

    if (blockIdx.y == 2) {       // ---- re row 128, bit-exact MFMA replay ----
        int lane = t & 63, wv = t >> 6;
        int fr = lane & 15;
        int fk = (lane >> 4) << 3;
        const u16* Ap = A1 + (size_t)(128 + fr) * 256;   // A rows 128..143
        const u16* Gb = G + (size_t)b * 65536;
        int c0 = blockIdx.x * 128 + wv * 32;             // 2 subtiles/wave
        f32x4 acc[2];
        acc[0] = (f32x4){0.f, 0.f, 0.f, 0.f};
        acc[1] = (f32x4){0.f, 0.f, 0.f, 0.f};
        for (int kk = 0; kk < 256; kk += 32) {
            short8 af = *(const short8*)(Ap + kk + fk);
#pragma unroll
            for (int sub = 0; sub < 2; ++sub) {
                short8 bfv = *(const short8*)(Gb + (size_t)(c0 + sub * 16 + fr) * 256 + kk + fk);
                acc[sub] = __builtin_amdgcn_mfma_f32_16x16x32_bf16(
                    af, bfv, acc[sub], 0, 0, 0);
            }
        }
        if ((lane >> 4) == 0) {  // fragment row 0 == Tt row 128 (reg 0)
            size_t base = (size_t)b * 65536 + 128 * 256;
            Tt_re[base + c0 + lane] = f2bf(acc[0][0]);
            Tt_re[base + c0 + 16 + lane] = f2bf(acc[1][0]);
        }
        return;
    }

    __shared__ u16 As[128 * 40];   // row stride 40 (16B-aligned, conflict-free)
    __shared__ u16 Bs[128 * 40];
    int r0 = blockIdx.y * 256;    // 0: re rows 0..127 (A1 0..127), 256: im (A1 256..383)
    int h0 = blockIdx.x * 128;    // 0,128
    int lane = t & 63, wv = t >> 6;
    int wr = (wv >> 1) * 64;
    int wc = (wv & 1) * 64;
    int fr = lane & 15;
    int fk = (lane >> 4) << 3;

    f32x4 acc[4][4];
#pragma unroll
    for (int i = 0; i < 4; ++i)
#pragma unroll
        for (int j = 0; j < 4; ++j) acc[i][j] = (f32x4){0.f, 0.f, 0.f, 0.f};

    const u16* Ap = A1 + (size_t)r0 * 256;
    const u16* Gp = G + (size_t)b * 65536 + (size_t)h0 * 256;

    for (int kk = 0; kk < 256; kk += 32) {
#pragma unroll
        for (int c = t; c < 512; c += 256) {
            int row = c >> 2, off = (c & 3) << 3;
            *(uint4*)&As[row * 40 + off] =
                *(const uint4*)(Ap + (size_t)row * 256 + kk + off);
            *(uint4*)&Bs[row * 40 + off] =
                *(const uint4*)(Gp + (size_t)row * 256 + kk + off);
        }
        __syncthreads();
        short8 af[4], bfr[4];
#pragma unroll
        for (int i = 0; i < 4; ++i)
            af[i] = *(const short8*)&As[(wr + i * 16 + fr) * 40 + fk];
#pragma unroll
        for (int j = 0; j < 4; ++j)
            bfr[j] = *(const short8*)&Bs[(wc + j * 16 + fr) * 40 + fk];
#pragma unroll
        for (int i = 0; i < 4; ++i)
#pragma unroll
            for (int j = 0; j < 4; ++j)
                acc[i][j] = __builtin_amdgcn_mfma_f32_16x16x32_bf16(
                    af[i], bfr[j], acc[i][j], 0, 0, 0);
        __syncthreads();
    }

    u16* dst = ((r0 < 256) ? Tt_re : Tt_im) + (size_t)b * 65536;
    int rq = (lane >> 4) << 2;
#pragma unroll
    for (int i = 0; i < 4; ++i)
#pragma unroll
        for (int j = 0; j < 4; ++j) {
            int col = h0 + wc + j * 16 + fr;
#pragma unroll
            for (int reg = 0; reg < 4; ++reg) {
                int row = wr + i * 16 + rq + reg;      // 0..127
                dst[(size_t)row * 256 + col] = f2bf(acc[i][j][reg]);
            }
        }
}

// ---------------------------------------------------------------------------
// s2f, paired-column form: 640 blocks.
// [0,512): GEMM, b=blk>>2, u0=((blk>>1)&1)*64, j0=(blk&1)*64, v in [j0,j0+64).
//   One staging of Ar/Ai/Br/Bi feeds FOUR bit-exact chains per (i,j):
//     col v      : accr1 = mfma(ar,br)∘mfma(-ai,bi);  acci1 = mfma(ar,bi)∘mfma(ai,br)
//     col 256-v  : accr2 = mfma(ar,br)∘mfma(ai,bi);   acci2 = mfma(ar,-bi)∘mfma(ai,br)
//   (old mirror blocks staged Br'=Tt_re[v], Bi'=-Tt_im[v]; (-a)(-b)==(a)(b)
//    bitwise, so these chains are bit-identical to the old 1024-block form.)
//   Pair shares one radial_bin + one sbins atomic (dx^2 = v^2 both).
//   j0==64 blocks additionally replay the old col-128 tile (B rows 128..143,
//   garbage rows only feed discarded columns) and keep the fr==0 column.
// [512,640): row128 (F[128,j] via fp32 dots, unchanged).
// ---------------------------------------------------------------------------
__global__ __launch_bounds__(256) void s2f(const u16* __restrict__ A1,
                                           const float* __restrict__ M_re,
                                           const u16* __restrict__ Tt_re,
                                           const u16* __restrict__ Tt_im,
                                           float* __restrict__ tbin) {
    __shared__ u16 Ar[64 * 40], Ai[64 * 40], Br[64 * 40], Bi[64 * 40];
    __shared__ u16 Br3[16 * 40], Bi3[16 * 40];
    __shared__ float sbins[NBINS];
    __shared__ float sM[256];
    int blk = blockIdx.x;
    int t = threadIdx.x;

    if (blk >= 512) {            // ---- row128 ----
        int b = blk - 512;
        sM[t] = M_re[128 * 256 + t];
        __syncthreads();
        if (t > 128) return;
        const u16* pr = Tt_re + (size_t)b * 65536 + (size_t)t * 256;
        const u16* pi = Tt_im + (size_t)b * 65536 + (size_t)t * 256;
        float re = 0.0f, im = 0.0f;
        for (int h = 0; h < 256; h += 8) {
            uint4 vr = *(const uint4*)(pr + h);
            uint4 vi = *(const uint4*)(pi + h);
            unsigned wr[4] = {vr.x, vr.y, vr.z, vr.w};
            unsigned wi[4] = {vi.x, vi.y, vi.z, vi.w};
#pragma unroll
            for (int q = 0; q < 4; ++q) {
                re = fmaf(sM[h + 2 * q], bf2f((u16)(wr[q] & 0xffff)), re);
                re = fmaf(sM[h + 2 * q + 1], bf2f((u16)(wr[q] >> 16)), re);
                im = fmaf(sM[h + 2 * q], bf2f((u16)(wi[q] & 0xffff)), im);
                im = fmaf(sM[h + 2 * q + 1], bf2f((u16)(wi[q] >> 16)), im);
            }
        }
        re += 1e-8f; im += 1e-8f;
        float mag = logf(sqrtf(re * re + im * im + 1e-10f) + 1e-10f);
        float wj = (t == 0 || t == 128) ? 1.0f : 2.0f;
        int dx = (t < 128) ? t : t - 256;
        int bin = radial_bin(dx, -128);
        atomicAdd(&tbin[b * NBINS + bin], wj * mag);
        return;
    }

    // ---- paired GEMM ----
    int b = blk >> 2;
    int u0 = ((blk >> 1) & 1) * 64;
    int j0 = (blk & 1) * 64;                 // v in [j0, j0+64), all < 128
    int lane = t & 63, wv = t >> 6;
    int wu = (wv >> 1) * 32;
    int wj = (wv & 1) * 32;
    int fr = lane & 15;
    int fk = (lane >> 4) << 3;
    bool do128 = (j0 == 64) && ((wv & 1) == 0);   // col-128 replay waves

    for (int i = t; i < NBINS; i += 256) sbins[i] = 0.0f;

    f32x4 accr1[2][2], acci1[2][2], accr2[2][2], acci2[2][2];
    f32x4 acc3r[2], acc3i[2];
#pragma unroll
    for (int i = 0; i < 2; ++i) {
#pragma unroll
        for (int j = 0; j < 2; ++j) {
            accr1[i][j] = (f32x4){0.f, 0.f, 0.f, 0.f};
            acci1[i][j] = (f32x4){0.f, 0.f, 0.f, 0.f};
            accr2[i][j] = (f32x4){0.f, 0.f, 0.f, 0.f};
            acci2[i][j] = (f32x4){0.f, 0.f, 0.f, 0.f};
        }
        acc3r[i] = (f32x4){0.f, 0.f, 0.f, 0.f};
        acc3i[i] = (f32x4){0.f, 0.f, 0.f, 0.f};
    }

    const u16* Apr = A1 + (size_t)u0 * 256;
    const u16* Api = A1 + (size_t)(256 + u0) * 256;

    int lrow = t >> 2, loff = (t & 3) << 3;
    const u16* Trs = Tt_re + (size_t)b * 65536 + (size_t)(j0 + lrow) * 256;
    const u16* Tis = Tt_im + (size_t)b * 65536 + (size_t)(j0 + lrow) * 256;
    // col-128 replay staging source (rows 128..143; rows >128 only feed
    // discarded columns): threads 0..63 -> Br3, 64..127 -> Bi3
    int r3 = (t & 63) >> 2, o3 = (t & 3) << 3;
    const u16* T3s = (((t >> 6) == 0) ? Tt_re : Tt_im)
                   + (size_t)b * 65536 + (size_t)(128 + r3) * 256;

    for (int kk = 0; kk < 256; kk += 32) {
        *(uint4*)&Ar[lrow * 40 + loff] =
            *(const uint4*)(Apr + (size_t)lrow * 256 + kk + loff);
        *(uint4*)&Ai[lrow * 40 + loff] =
            *(const uint4*)(Api + (size_t)lrow * 256 + kk + loff);
        *(uint4*)&Br[lrow * 40 + loff] = *(const uint4*)(Trs + kk + loff);
        *(uint4*)&Bi[lrow * 40 + loff] = *(const uint4*)(Tis + kk + loff);
        if (j0 == 64 && t < 128) {
            uint4 v3 = *(const uint4*)(T3s + kk + o3);
            if (t < 64) *(uint4*)&Br3[r3 * 40 + o3] = v3;
            else        *(uint4*)&Bi3[r3 * 40 + o3] = v3;
        }
        __syncthreads();
        short8 arf[2], aif[2], naif[2], brf[2], bif[2], nbif[2];
#pragma unroll
        for (int i = 0; i < 2; ++i) {
            arf[i] = *(const short8*)&Ar[(wu + i * 16 + fr) * 40 + fk];
            aif[i] = *(const short8*)&Ai[(wu + i * 16 + fr) * 40 + fk];
            naif[i] = negbf(aif[i]);
        }
#pragma unroll
        for (int j = 0; j < 2; ++j) {
            brf[j] = *(const short8*)&Br[(wj + j * 16 + fr) * 40 + fk];
            bif[j] = *(const short8*)&Bi[(wj + j * 16 + fr) * 40 + fk];
            nbif[j] = negbf(bif[j]);
        }
#pragma unroll
        for (int i = 0; i < 2; ++i)
#pragma unroll
            for (int j = 0; j < 2; ++j) {
                accr1[i][j] = __builtin_amdgcn_mfma_f32_16x16x32_bf16(
                    arf[i], brf[j], accr1[i][j], 0, 0, 0);
                accr1[i][j] = __builtin_amdgcn_mfma_f32_16x16x32_bf16(
                    naif[i], bif[j], accr1[i][j], 0, 0, 0);
                acci1[i][j] = __builtin_amdgcn_mfma_f32_16x16x32_bf16(
                    arf[i], bif[j], acci1[i][j], 0, 0, 0);
                acci1[i][j] = __builtin_amdgcn_mfma_f32_16x16x32_bf16(
                    aif[i], brf[j], acci1[i][j], 0, 0, 0);
                accr2[i][j] = __builtin_amdgcn_mfma_f32_16x16x32_bf16(
                    arf[i], brf[j], accr2[i][j], 0, 0, 0);
                accr2[i][j] = __builtin_amdgcn_mfma_f32_16x16x32_bf16(
                    aif[i], bif[j], accr2[i][j], 0, 0, 0);
                acci2[i][j] = __builtin_amdgcn_mfma_f32_16x16x32_bf16(
                    arf[i], nbif[j], acci2[i][j], 0, 0, 0);
                acci2[i][j] = __builtin_amdgcn_mfma_f32_16x16x32_bf16(
                    aif[i], brf[j], acci2[i][j], 0, 0, 0);
            }
        if (do128) {
            short8 brf3 = *(const short8*)&Br3[fr * 40 + fk];
            short8 bif3 = *(const short8*)&Bi3[fr * 40 + fk];
#pragma unroll
            for (int i = 0; i < 2; ++i) {
                acc3r[i] = __builtin_amdgcn_mfma_f32_16x16x32_bf16(
                    arf[i], brf3, acc3r[i], 0, 0, 0);
                acc3r[i] = __builtin_amdgcn_mfma_f32_16x16x32_bf16(
                    naif[i], bif3, acc3r[i], 0, 0, 0);
                acc3i[i] = __builtin_amdgcn_mfma_f32_16x16x32_bf16(
                    arf[i], bif3, acc3i[i], 0, 0, 0);
                acc3i[i] = __builtin_amdgcn_mfma_f32_16x16x32_bf16(
                    aif[i], brf3, acc3i[i], 0, 0, 0);
            }
        }
        __syncthreads();
    }

    int rq = (lane >> 4) << 2;
#pragma unroll
    for (int i = 0; i < 2; ++i)
#pragma unroll
        for (int j = 0; j < 2; ++j) {
            int v = j0 + wj + j * 16 + fr;            // 0..127, dx = v
#pragma unroll
            for (int reg = 0; reg < 4; ++reg) {
                int u = u0 + wu + i * 16 + rq + reg;  // 0..127
                float wrow = (u == 0) ? 1.0f : 2.0f;
                float re1 = accr1[i][j][reg] + 1e-8f;
                float im1 = acci1[i][j][reg] + 1e-8f;
                float m1 = logf(sqrtf(re1 * re1 + im1 * im1 + 1e-10f) + 1e-10f);
                float val;
                if (v == 0) {
                    val = wrow * m1;                  // column 256-v doesn't exist
                } else {
                    float re2 = accr2[i][j][reg] + 1e-8f;
                    float im2 = acci2[i][j][reg] + 1e-8f;
                    float m2 = logf(sqrtf(re2 * re2 + im2 * im2 + 1e-10f) + 1e-10f);
                    val = wrow * (m1 + m2);           // same bin: dx^2 equal
                }
                int bin = radial_bin(v, u);
                atomicAdd(&sbins[bin], val);
            }
        }
    if (do128 && fr == 0) {      // col-128 replay epilogue (kept column only)
#pragma unroll
        for (int i = 0; i < 2; ++i)
#pragma unroll
            for (int reg = 0; reg < 4; ++reg) {
                int u = u0 + wu + i * 16 + rq + reg;
                float wrow = (u == 0) ? 1.0f : 2.0f;
                float re = acc3r[i][reg] + 1e-8f;
                float im = acc3i[i][reg] + 1e-8f;
                float mag = logf(sqrtf(re * re + im * im + 1e-10f) + 1e-10f);
                int bin = radial_bin(-128, u);
                atomicAdd(&sbins[bin], wrow * mag);
            }
    }
    __syncthreads();
    for (int i = t; i < NBINS; i += 256)
        atomicAdd(&tbin[b * NBINS + i], sbins[i]);
}

// ---------------------------------------------------------------------------
// Finalize: nr = column-sum of nrpart; prof = tbin/nr; min-max over 1..179;
// dot bins 90..179 with w.
// ---------------------------------------------------------------------------
__global__ __launch_bounds__(192) void finalize(const float* __restrict__ tbin,
                                                const float* __restrict__ nrpart,
                                                const float* __restrict__ w,
                                                const float* __restrict__ bias,
                                                float* __restrict__ out) {
    __shared__ float prof[NBINS];
    __shared__ float smn, smx, ssum;
    int b = blockIdx.x;
    int t = threadIdx.x;
    if (t < NBINS) {
        float nr = 0.0f;
        for (int i = 0; i < 256; ++i) nr += nrpart[i * NBINS + t];
        prof[t] = tbin[b * NBINS + t] / (nr + 1e-10f);
    }
    __syncthreads();
    if (t == 0) {
        float mn = prof[1], mx = prof[1];
        for (int i = 2; i <= 179; ++i) {
            float p = prof[i];
            mn = fminf(mn, p);
            mx = fmaxf(mx, p);
        }
        smn = mn; smx = mx; ssum = 0.0f;
    }
    __syncthreads();
    if (t < 90) {
        float denom = smx - smn;
        float v = (prof[90 + t] - smn) / denom;
        if (v != v) v = 0.0f;
        atomicAdd(&ssum, v * w[t]);
    }
    __syncthreads();
    if (t == 0) out[b] = ssum + bias[0];
}

// ---------------------------------------------------------------------------
extern "C" void kernel_launch(void* const* d_in, const int* in_sizes, int n_in,
                              void* d_out, int out_size, void* d_ws, size_t ws_size,
                              hipStream_t stream) {
    const float* x = (const float*)d_in[0];     // (128,3,256,256)
    const float* w = (const float*)d_in[1];     // (1,90)
    const float* bias = (const float*)d_in[2];  // (1,)
    float* out = (float*)d_out;                 // (128,1)

    float* M_re = (float*)d_ws;                    // 65536 f
    float* M_im = M_re + 65536;                    // 65536 f
    u16* A1 = (u16*)(M_im + 65536);                // 512*256 u16
    u16* G = A1 + 131072;                          // 128*65536 u16
    u16* Tt_re = G + (size_t)NB * 65536;           // 128*65536 u16 (rows 0..128 used)
    u16* Tt_im = Tt_re + (size_t)NB * 65536;       // 128*65536 u16 (rows 0..128 used)
    float* tbin = (float*)(Tt_im + (size_t)NB * 65536);   // NB*NBINS f
    float* nrpart = tbin + NB * NBINS;             // 256*NBINS f

    prep<<<1568, 256, 0, stream>>>(x, G, M_re, M_im, A1, nrpart, tbin, Tt_im);
    s1<<<dim3(2, 3, NB), 256, 0, stream>>>(A1, G, Tt_re, Tt_im);
    s2f<<<640, 256, 0, stream>>>(A1, M_re, Tt_re, Tt_im, tbin);
    finalize<<<NB, 192, 0, stream>>>(tbin, nrpart, w, bias, out);
}